// Round 5
// baseline (714.059 us; speedup 1.0000x reference)
//
#include <hip/hip_runtime.h>
#include <hip/hip_bf16.h>

// Problem dims
#define B_ 1024
#define I_ 512
#define O_ 512
#define M_ 8
#define R_ 512
#define A_ 16
#define D_ 128   // M_*A_
#define NLEV 11  // squaring levels: k = 2^j, j=0..11

using bf16 = __hip_bfloat16;
typedef __attribute__((ext_vector_type(8))) short bf16x8;
typedef __attribute__((ext_vector_type(4))) float f32x4;

__device__ __forceinline__ short f2b(float x){
  __hip_bfloat16 h = __float2bfloat16(x);
  union { __hip_bfloat16 h; short s; } u; u.h = h; return u.s;
}
__device__ __forceinline__ float s2f(short s){
  union { short s[2]; float f; } u; u.s[0] = 0; u.s[1] = s; return u.f;
}

// ---------------------------------------------------------------------------
// MFMA bf16 GEMM template (main pipeline): 64x64 tile, BK=32, 256 threads.
// Operands via fp32 functors, converted to bf16 in LDS. (unchanged from R4)
// ---------------------------------------------------------------------------
template<int SKL, class FA, class FB, class FC>
__global__ __launch_bounds__(256) void gemm_mfma(FA fa, FB fb, FC fc, int Ktot){
  __shared__ __align__(16) short As[64][40];   // [m][k]
  __shared__ __align__(16) short Bs[64][40];   // [n][k]
  const int t = threadIdx.x;
  const int wv = t >> 6, lane = t & 63;
  const int row0 = blockIdx.y * 64, col0 = blockIdx.x * 64;
  const int kseg = Ktot >> SKL;
  const int kbeg = (blockIdx.z & ((1 << SKL) - 1)) * kseg;
  const int sr = t >> 2, sk = (t & 3) * 8;
  const int wr = (wv >> 1) * 32, wc = (wv & 1) * 32;
  const int fm = lane & 15, fq = lane >> 4;
  f32x4 zz = {0.f, 0.f, 0.f, 0.f};
  f32x4 acc[2][2] = {{zz, zz}, {zz, zz}};
  for (int k0 = 0; k0 < kseg; k0 += 32){
    float av[8], bv[8];
    #pragma unroll
    for (int j = 0; j < 8; ++j) av[j] = fa(row0 + sr, kbeg + k0 + sk + j);
    #pragma unroll
    for (int j = 0; j < 8; ++j) bv[j] = fb(kbeg + k0 + sk + j, col0 + sr);
    __syncthreads();
    bf16x8 pa, pb;
    #pragma unroll
    for (int j = 0; j < 8; ++j){ pa[j] = f2b(av[j]); pb[j] = f2b(bv[j]); }
    *(bf16x8*)&As[sr][sk] = pa;
    *(bf16x8*)&Bs[sr][sk] = pb;
    __syncthreads();
    bf16x8 af[2], bfr[2];
    #pragma unroll
    for (int i = 0; i < 2; ++i){
      af[i]  = *(const bf16x8*)&As[wr + i * 16 + fm][fq * 8];
      bfr[i] = *(const bf16x8*)&Bs[wc + i * 16 + fm][fq * 8];
    }
    #pragma unroll
    for (int i = 0; i < 2; ++i)
      #pragma unroll
      for (int j = 0; j < 2; ++j)
        acc[i][j] = __builtin_amdgcn_mfma_f32_16x16x32_bf16(af[i], bfr[j], acc[i][j], 0, 0, 0);
  }
  #pragma unroll
  for (int i = 0; i < 2; ++i)
    #pragma unroll
    for (int j = 0; j < 2; ++j)
      #pragma unroll
      for (int r = 0; r < 4; ++r)
        fc(row0 + wr + i * 16 + fq * 4 + r, col0 + wc + j * 16 + fm, acc[i][j][r]);
}

// ------------------------- operand functors (fp32 sources) ------------------
struct AXi  { const float* p; __device__ float operator()(int r, int k) const { return p[r * I_ + k]; } };
struct BWx  { const float* p; __device__ float operator()(int k, int c) const { return p[(c >> 4) * (512 * A_) + k * A_ + (c & 15)]; } };
struct CQ   { float* p; __device__ void operator()(int r, int c, float v) const { p[r * D_ + c] = v; } };
struct ASi  { const float* p; __device__ float operator()(int r, int k) const { return p[r * R_ + k]; } };
struct CKV  { float* p; __device__ void operator()(int r, int c, float v) const {
  int b = r >> 3, n = r & 7, m = c >> 4, a = c & 15;
  p[b * 1024 + m * 128 + n * 16 + a] = v; } };
struct APre { const float* ui; const float* si; const float* sc; __device__ float operator()(int r, int k) const {
  int m = blockIdx.z;
  if (k < D_) return ui[(r * M_ + m) * D_ + k];
  return sc[m] * si[(r * M_ + m) * R_ + (k - D_)]; } };
struct BPre { const float* win; const float* w; __device__ float operator()(int k, int c) const {
  int m = blockIdx.z;
  if (k < D_) return win[m * (D_ * R_) + k * R_ + c];
  return w[m * (R_ * R_) + (k - D_) * R_ + c]; } };
struct CPre { float* p; __device__ void operator()(int r, int c, float v) const {
  p[(r * M_ + blockIdx.z) * R_ + c] = v; } };
struct AYi  { const float* p; __device__ float operator()(int r, int k) const { return p[r * 4096 + k]; } };
struct BYi  { const float* p; __device__ float operator()(int k, int c) const { return p[k * O_ + c]; } };
struct CYiA { float* p; __device__ void operator()(int r, int c, float v) const { atomicAdd(&p[r * O_ + c], v); } };

// ---------------------------------------------------------------------------
// Eigen chain v2: bf16 X + bf16 X^T per level; split-K=2 squaring into fp32
// partials; combine applies pending scale s^2=1/norm2[lev-1], emits X/X^T,
// accumulates norm2[lev]. L-recursion semantics identical to R4.
// ---------------------------------------------------------------------------
__global__ void k_init(float* norm2){
  int t = threadIdx.x;
  if (t < 8 * (NLEV + 1)) norm2[t] = 0.f;
}

__global__ __launch_bounds__(256) void k_zero(float* p){
  const int t = threadIdx.x;
  #pragma unroll
  for (int e = 0; e < 4; ++e) p[blockIdx.x * 1024 + e * 256 + t] = 0.f;
}

// W (fp32) -> X0 bf16 + X0^T bf16 + norm2[0] (over bf16-rounded values)
__global__ __launch_bounds__(256) void k_prep(const float* W, short* X, short* XT, float* norm2){
  __shared__ float tile[64][65];
  const int u = blockIdx.z, t = threadIdx.x, lane = t & 63;
  const int row0 = blockIdx.y * 64, col0 = blockIdx.x * 64;
  const float* Wm = W + (size_t)u * (R_ * R_);
  short* Xm  = X  + (size_t)u * (R_ * R_);
  short* XTm = XT + (size_t)u * (R_ * R_);
  float ss = 0.f;
  #pragma unroll
  for (int l = 0; l < 16; ++l){
    int idx = l * 256 + t, r = idx >> 6, c = idx & 63;
    short b = f2b(Wm[(row0 + r) * R_ + col0 + c]);
    float vb = s2f(b);
    tile[r][c] = vb;
    Xm[(row0 + r) * R_ + col0 + c] = b;
    ss = fmaf(vb, vb, ss);
  }
  __syncthreads();
  #pragma unroll
  for (int l = 0; l < 16; ++l){
    int idx = l * 256 + t, r = idx >> 6, c = idx & 63;
    XTm[(col0 + r) * R_ + row0 + c] = f2b(tile[c][r]);
  }
  #pragma unroll
  for (int o = 32; o > 0; o >>= 1) ss += __shfl_xor(ss, o, 64);
  if (lane == 0) atomicAdd(&norm2[u], ss);
}

// P_half = X*X over half the K range; bf16 coalesced staging, no conversion.
__global__ __launch_bounds__(256) void k_sq2(const short* X, const short* XT,
                                             float* part0, float* part1){
  __shared__ __align__(16) short As[64][40];
  __shared__ __align__(16) short Bs[64][40];
  const int t = threadIdx.x;
  const int wv = t >> 6, lane = t & 63;
  const int u = blockIdx.z & 7, kh = blockIdx.z >> 3;
  const int row0 = blockIdx.y * 64, col0 = blockIdx.x * 64, kbeg = kh * 256;
  const short* Xm  = X  + (size_t)u * (R_ * R_);
  const short* XTm = XT + (size_t)u * (R_ * R_);
  float* dst = (kh ? part1 : part0) + (size_t)u * (R_ * R_);
  const int sr = t >> 2, sk = (t & 3) * 8;
  const int wr = (wv >> 1) * 32, wc = (wv & 1) * 32;
  const int fm = lane & 15, fq = lane >> 4;
  f32x4 zz = {0.f, 0.f, 0.f, 0.f};
  f32x4 acc[2][2] = {{zz, zz}, {zz, zz}};
  for (int k0 = 0; k0 < 256; k0 += 32){
    bf16x8 a8 = *(const bf16x8*)&Xm [(row0 + sr) * R_ + kbeg + k0 + sk];
    bf16x8 b8 = *(const bf16x8*)&XTm[(col0 + sr) * R_ + kbeg + k0 + sk];
    __syncthreads();
    *(bf16x8*)&As[sr][sk] = a8;
    *(bf16x8*)&Bs[sr][sk] = b8;
    __syncthreads();
    bf16x8 af[2], bfr[2];
    #pragma unroll
    for (int i = 0; i < 2; ++i){
      af[i]  = *(const bf16x8*)&As[wr + i * 16 + fm][fq * 8];
      bfr[i] = *(const bf16x8*)&Bs[wc + i * 16 + fm][fq * 8];
    }
    #pragma unroll
    for (int i = 0; i < 2; ++i)
      #pragma unroll
      for (int j = 0; j < 2; ++j)
        acc[i][j] = __builtin_amdgcn_mfma_f32_16x16x32_bf16(af[i], bfr[j], acc[i][j], 0, 0, 0);
  }
  #pragma unroll
  for (int i = 0; i < 2; ++i)
    #pragma unroll
    for (int j = 0; j < 2; ++j)
      #pragma unroll
      for (int r = 0; r < 4; ++r)
        dst[(row0 + wr + i * 16 + fq * 4 + r) * R_ + col0 + wc + j * 16 + fm] = acc[i][j][r];
}

// X_lev = s^2*(p0+p1) (bf16), X_lev^T, norm2[lev] (over bf16-rounded values)
__global__ __launch_bounds__(256) void k_comb(const float* p0, const float* p1,
                                              float* norm2, short* X, short* XT, int lev){
  __shared__ float tile[64][65];
  const int u = blockIdx.z, t = threadIdx.x, lane = t & 63;
  const int row0 = blockIdx.y * 64, col0 = blockIdx.x * 64;
  const float s2 = 1.f / norm2[(lev - 1) * 8 + u];
  const float* p0m = p0 + (size_t)u * (R_ * R_);
  const float* p1m = p1 + (size_t)u * (R_ * R_);
  short* Xm  = X  + (size_t)u * (R_ * R_);
  short* XTm = XT + (size_t)u * (R_ * R_);
  float ss = 0.f;
  #pragma unroll
  for (int l = 0; l < 16; ++l){
    int idx = l * 256 + t, r = idx >> 6, c = idx & 63;
    int g = (row0 + r) * R_ + col0 + c;
    short b = f2b(s2 * (p0m[g] + p1m[g]));
    float vb = s2f(b);
    tile[r][c] = vb;
    Xm[g] = b;
    ss = fmaf(vb, vb, ss);
  }
  __syncthreads();
  #pragma unroll
  for (int l = 0; l < 16; ++l){
    int idx = l * 256 + t, r = idx >> 6, c = idx & 63;
    XTm[(col0 + r) * R_ + row0 + c] = f2b(tile[c][r]);
  }
  #pragma unroll
  for (int o = 32; o > 0; o >>= 1) ss += __shfl_xor(ss, o, 64);
  if (lane == 0) atomicAdd(&norm2[lev * 8 + u], ss);
}

// L_j = 2 L_{j-1} + 0.5 ln n2_j ; lnrho = (L11 - 2 L10 + L9)/512
__global__ void k_rho(const float* norm2, const float* sr, float* sscale){
  int t = threadIdx.x;
  if (t < 8){
    float L = 0.5f * logf(norm2[t]);
    float L9 = 0.f, L10 = 0.f, L11 = 0.f;
    for (int j = 1; j <= NLEV; ++j){
      L = 2.f * L + 0.5f * logf(norm2[j * 8 + t]);
      if (j == 9)  L9  = L;
      if (j == 10) L10 = L;
      if (j == 11) L11 = L;
    }
    float lnr = (L11 - 2.f * L10 + L9) * (1.f / 512.f);
    sscale[t] = sr[t] / expf(lnr);
  }
}

// ---------------------------------------------------------------------------
// Attention: one wave per (b,m). lane = q*8+n.
// ---------------------------------------------------------------------------
__global__ __launch_bounds__(256) void k_attn(const float* Q, const float* K, const float* V, float* Ui){
  __shared__ float sQ[4][128], sK[4][128], sV[4][128], sA[4][64];
  const int wib = threadIdx.x >> 6, lane = threadIdx.x & 63;
  const int w = blockIdx.x * 4 + wib;
  const int b = w >> 3, m = w & 7;
  for (int e = lane; e < 128; e += 64){
    sQ[wib][e] = Q[b * 128 + e];
    sK[wib][e] = K[b * 1024 + m * 128 + e];
    sV[wib][e] = V[b * 1024 + m * 128 + e];
  }
  __syncthreads();
  const int q = lane >> 3, n = lane & 7;
  float s = 0.f;
  #pragma unroll
  for (int a = 0; a < 16; ++a) s = fmaf(sQ[wib][q * 16 + a], sK[wib][n * 16 + a], s);
  float mx = s;
  for (int d2 = 1; d2 < 8; d2 <<= 1) mx = fmaxf(mx, __shfl_xor(mx, d2, 64));
  float p = expf(s - mx);
  float sm = p;
  for (int d2 = 1; d2 < 8; d2 <<= 1) sm += __shfl_xor(sm, d2, 64);
  float ai = p / (sm * 11.313708498984761f);   // softmax then /sqrt(128)
  sA[wib][q * 8 + n] = ai;
  __syncthreads();
  for (int e = lane; e < 128; e += 64){
    int q2 = e >> 4, a2 = e & 15;
    float acc = 0.f;
    #pragma unroll
    for (int n2 = 0; n2 < 8; ++n2) acc = fmaf(sA[wib][q2 * 8 + n2], sV[wib][n2 * 16 + a2], acc);
    Ui[(b * 8 + m) * 128 + e] = acc;
  }
}

// Snew = (1-lr)*Si + lr*tanh(pre + bias)
__global__ __launch_bounds__(256) void k_final_ew(const float* pre, const float* bias, const float* lr,
                                                  const float* Si, float* outSnew){
  const int t = threadIdx.x;
  for (int e = 0; e < 4; ++e){
    int idx = blockIdx.x * 1024 + e * 256 + t;
    int m = (idx >> 9) & 7, r = idx & 511;
    float v  = pre[idx] + bias[m * 512 + r];
    float tt = tanhf(v);
    float l  = lr[m];
    outSnew[idx] = (1.f - l) * Si[idx] + l * tt;
  }
}

// ---------------------------------------------------------------------------
extern "C" void kernel_launch(void* const* d_in, const int* in_sizes, int n_in,
                              void* d_out, int out_size, void* d_ws, size_t ws_size,
                              hipStream_t stream) {
  const float* Xi   = (const float*)d_in[0];
  const float* Si   = (const float*)d_in[1];
  const float* Wq   = (const float*)d_in[2];
  const float* Wk   = (const float*)d_in[3];
  const float* Wv   = (const float*)d_in[4];
  const float* Wout = (const float*)d_in[5];
  const float* W    = (const float*)d_in[6];
  const float* Win  = (const float*)d_in[7];
  const float* bias = (const float*)d_in[8];
  const float* sr   = (const float*)d_in[9];
  const float* lr   = (const float*)d_in[10];

  float* ws = (float*)d_ws;
  float* part0 = ws + 0;         // 2,097,152 fp32 (8 MB)
  float* part1 = ws + 2097152;   // 2,097,152
  float* preb  = ws + 0;         // 4,194,304 — aliases partials, used after chain
  float* Qb    = ws + 4194304;   // 131,072
  float* Kb    = ws + 4325376;   // 1,048,576
  float* Vb    = ws + 5373952;   // 1,048,576
  float* Uib   = ws + 6422528;   // 1,048,576
  float* norm2 = ws + 7471104;   // 96
  float* sscal = ws + 7471200;   // 8
  short* Xc    = (short*)(ws + 7471232);   // bf16 8x512x512 (4 MB)
  short* XTc   = (short*)(ws + 8519808);   // bf16 transpose (4 MB)
  // total 9,568,384 floats = 38.27 MB (R3 proved this fits)

  float* outYi   = (float*)d_out;            // [1024,512]
  float* outSnew = (float*)d_out + 524288;   // [1024,8,512]

  // ---- spectral radius chain ----
  k_init<<<1, 128, 0, stream>>>(norm2);
  k_zero<<<512, 256, 0, stream>>>(outYi);    // for split-K atomic Yi epilogue
  k_prep<<<dim3(8, 8, 8), 256, 0, stream>>>(W, Xc, XTc, norm2);
  for (int j = 1; j <= NLEV; ++j){
    k_sq2<<<dim3(8, 8, 16), 256, 0, stream>>>(Xc, XTc, part0, part1);
    k_comb<<<dim3(8, 8, 8), 256, 0, stream>>>(part0, part1, norm2, Xc, XTc, j);
  }
  k_rho<<<1, 64, 0, stream>>>(norm2, sr, sscal);

  // ---- main pipeline (MFMA bf16) ----
  gemm_mfma<0><<<dim3(2, 16), 256, 0, stream>>>(AXi{Xi}, BWx{Wq}, CQ{Qb}, 512);
  gemm_mfma<0><<<dim3(2, 128), 256, 0, stream>>>(ASi{Si}, BWx{Wk}, CKV{Kb}, 512);
  gemm_mfma<0><<<dim3(2, 128), 256, 0, stream>>>(ASi{Si}, BWx{Wv}, CKV{Vb}, 512);
  k_attn<<<2048, 256, 0, stream>>>(Qb, Kb, Vb, Uib);
  gemm_mfma<0><<<dim3(8, 16, 8), 256, 0, stream>>>(APre{Uib, Si, sscal}, BPre{Win, W}, CPre{preb}, 640);
  k_final_ew<<<4096, 256, 0, stream>>>(preb, bias, lr, Si, outSnew);
  gemm_mfma<2><<<dim3(8, 16, 4), 256, 0, stream>>>(AYi{outSnew}, BYi{Wout}, CYiA{outYi}, 4096);
}